// Round 3
// baseline (531.457 us; speedup 1.0000x reference)
//
#include <hip/hip_runtime.h>
#include <hip/hip_bf16.h>

// GraphSAGE 3-layer + pool + linear. MFMA bf16-split GEMM design (R3):
//   value v ~= hi + lo (both bf16, RNE).  C = A·W via logical K=384/source:
//   j-chunks: [Ahi0·Whi0, Ahi1·Whi1, Ahi0·Wlo0, Ahi1·Wlo1, Alo0·Whi0, Alo1·Whi1]
//   (drops only lo·lo ~ 2^-18 relative). Two sources (agg, h) -> 12 chunks of 64.
// Activations stored packed: u32 = (hi16<<16)|lo16, value = asf(u&0xFFFF0000)+asf(u<<16).

#define FH 128
#define OUTD 256
#define SCHUNK 2048

typedef unsigned int u32;
typedef unsigned short u16;
typedef __attribute__((ext_vector_type(8))) short bf8frag;
typedef __attribute__((ext_vector_type(4))) float f4frag;

__device__ inline u32 pack_bf16pair(float v) {
    u32 b = __float_as_uint(v);
    u32 hb = (b + 0x7FFFu + ((b >> 16) & 1u)) & 0xFFFF0000u;
    float rem = v - __uint_as_float(hb);
    u32 rb = __float_as_uint(rem);
    u32 lb = ((rb + 0x7FFFu + ((rb >> 16) & 1u)) >> 16) & 0xFFFFu;
    return hb | lb;
}
__device__ inline float unpack_f(u32 u) {
    return __uint_as_float(u & 0xFFFF0000u) + __uint_as_float(u << 16);
}

// ---------------------------------------------------------------- histogram
__global__ void hist_kernel(const int* __restrict__ dst, int* __restrict__ cnt, int E) {
    int e = blockIdx.x * 256 + threadIdx.x;
    if (e < E) atomicAdd(&cnt[dst[e]], 1);
}

// ---------------------------------------------- scan pass A: per-block sums
__global__ void scanA_kernel(const int* __restrict__ cnt, int* __restrict__ bsum, int n) {
    __shared__ int ws[4];
    int b = blockIdx.x, t = threadIdx.x;
    int base = b * SCHUNK + t * 8;
    int s = 0;
    #pragma unroll
    for (int k = 0; k < 8; ++k) {
        int i = base + k;
        s += (i < n) ? cnt[i] : 0;
    }
    #pragma unroll
    for (int off = 32; off >= 1; off >>= 1) s += __shfl_xor(s, off, 64);
    int w = t >> 6, lane = t & 63;
    if (lane == 0) ws[w] = s;
    __syncthreads();
    if (t == 0) bsum[b] = ws[0] + ws[1] + ws[2] + ws[3];
}

// ------------------------------- scan pass B: scan block sums (1 wave)
__global__ void scanB_kernel(const int* __restrict__ bsum, int* __restrict__ boff,
                             int* __restrict__ rp, int B, int n) {
    int t = threadIdx.x;  // 64 threads
    int v = (t < B) ? bsum[t] : 0;
    int x = v;
    #pragma unroll
    for (int off = 1; off < 64; off <<= 1) {
        int y = __shfl_up(x, off, 64);
        if (t >= off) x += y;
    }
    if (t < B) boff[t] = x - v;
    if (t == 63) rp[n] = x;
}

// --------------------------- scan pass C: full exclusive scan + emit rp/dinv
__global__ void scanC_kernel(const int* __restrict__ cnt, const int* __restrict__ boff,
                             int* __restrict__ rp, float* __restrict__ dinv, int n) {
    __shared__ int ws[4];
    int b = blockIdx.x, t = threadIdx.x;
    int base = b * SCHUNK + t * 8;
    int v[8];
    int ts = 0;
    #pragma unroll
    for (int k = 0; k < 8; ++k) {
        int i = base + k;
        v[k] = (i < n) ? cnt[i] : 0;
        ts += v[k];
    }
    int w = t >> 6, lane = t & 63;
    int x = ts;
    #pragma unroll
    for (int off = 1; off < 64; off <<= 1) {
        int y = __shfl_up(x, off, 64);
        if (lane >= off) x += y;
    }
    if (lane == 63) ws[w] = x;
    __syncthreads();
    int woff = 0;
    #pragma unroll
    for (int q = 0; q < 4; ++q) woff += (q < w) ? ws[q] : 0;
    int run = boff[b] + woff + (x - ts);
    #pragma unroll
    for (int k = 0; k < 8; ++k) {
        int i = base + k;
        if (i < n) {
            rp[i] = run;
            dinv[i] = 1.0f / (float)max(v[k], 1);
        }
        run += v[k];
    }
}

// --------------------------------------------------------- CSR edge scatter
__global__ void scatter_kernel(const int* __restrict__ src, const int* __restrict__ dst,
                               const int* __restrict__ rp, int* __restrict__ cursor,
                               int* __restrict__ esrc, int E) {
    int e = blockIdx.x * 256 + threadIdx.x;
    if (e < E) {
        int d = dst[e];
        int pos = rp[d] + atomicAdd(&cursor[d], 1);
        esrc[pos] = src[e];
    }
}

// ------------------------------------------------------- graph range bounds
__global__ void graph_bounds_kernel(const int* __restrict__ batch, int* __restrict__ gstart,
                                    int n, int g) {
    int i = blockIdx.x * 256 + threadIdx.x;
    if (i >= n) return;
    int b = batch[i];
    int pb = (i == 0) ? -1 : batch[i - 1];
    for (int q = pb + 1; q <= b; ++q) gstart[q] = i;
    if (i == n - 1) {
        for (int q = b + 1; q <= g; ++q) gstart[q] = n;
    }
}

// ---------------------------------------------------------- prep: x -> packed
__global__ void prep_x(const float* __restrict__ x, u32* __restrict__ hP, int n4) {
    int id = blockIdx.x * 256 + threadIdx.x;
    if (id >= n4) return;
    float4 v = *(const float4*)(x + (size_t)id * 4);
    u32 o0 = pack_bf16pair(v.x), o1 = pack_bf16pair(v.y);
    u32 o2 = pack_bf16pair(v.z), o3 = pack_bf16pair(v.w);
    uint4 o = {o0, o1, o2, o3};
    *(uint4*)(hP + (size_t)id * 4) = o;
}

// ------------------------------------------- prep: weights -> bf16 hi/lo/hi
// Wp[arr][o][384]: cols 0-127 = hi(W[o][:]), 128-255 = lo, 256-383 = hi again
__global__ void prep_w(const float* __restrict__ W0, const float* __restrict__ W1,
                       const float* __restrict__ W2, const float* __restrict__ W3,
                       const float* __restrict__ W4, const float* __restrict__ W5,
                       u16* __restrict__ Wp) {
    const float* Ws[6] = {W0, W1, W2, W3, W4, W5};
    const float* W = Ws[blockIdx.x];
    int o = threadIdx.x;  // 128
    u16* row = Wp + ((size_t)blockIdx.x * 128 + o) * 384;
    for (int f = 0; f < 128; ++f) {
        float v = W[o * 128 + f];
        u32 b = __float_as_uint(v);
        u32 hb = (b + 0x7FFFu + ((b >> 16) & 1u)) & 0xFFFF0000u;
        float rem = v - __uint_as_float(hb);
        u32 rb = __float_as_uint(rem);
        u32 lb = (rb + 0x7FFFu + ((rb >> 16) & 1u)) & 0xFFFF0000u;
        row[f] = (u16)(hb >> 16);
        row[128 + f] = (u16)(lb >> 16);
        row[256 + f] = (u16)(hb >> 16);
    }
}

// --------------------------------------------------- mean aggregation (CSR)
// half-wave (32 lanes) per node; lane covers 4 features; x4 unroll for MLP.
// layer 1 reads fp32 x; layers 2,3 read packed h. Output: packed aggP.
__global__ void agg_kernel(const float* __restrict__ xf, const u32* __restrict__ hP,
                           const int* __restrict__ rp, const int* __restrict__ esrc,
                           const float* __restrict__ dinv,
                           u32* __restrict__ aggP, int n_nodes) {
    int node = blockIdx.x * 8 + (threadIdx.x >> 5);
    if (node >= n_nodes) return;
    int lane = threadIdx.x & 31;
    int f = lane * 4;
    int s0 = rp[node], s1 = rp[node + 1];
    float4 a0 = {0.f, 0.f, 0.f, 0.f};
    float4 a1 = a0, a2 = a0, a3 = a0;
    int j = s0;
    if (xf) {
        for (; j + 4 <= s1; j += 4) {
            int i0 = esrc[j], i1 = esrc[j + 1], i2 = esrc[j + 2], i3 = esrc[j + 3];
            float4 v0 = *(const float4*)(xf + (size_t)i0 * FH + f);
            float4 v1 = *(const float4*)(xf + (size_t)i1 * FH + f);
            float4 v2 = *(const float4*)(xf + (size_t)i2 * FH + f);
            float4 v3 = *(const float4*)(xf + (size_t)i3 * FH + f);
            a0.x += v0.x; a0.y += v0.y; a0.z += v0.z; a0.w += v0.w;
            a1.x += v1.x; a1.y += v1.y; a1.z += v1.z; a1.w += v1.w;
            a2.x += v2.x; a2.y += v2.y; a2.z += v2.z; a2.w += v2.w;
            a3.x += v3.x; a3.y += v3.y; a3.z += v3.z; a3.w += v3.w;
        }
        for (; j < s1; ++j) {
            float4 v0 = *(const float4*)(xf + (size_t)esrc[j] * FH + f);
            a0.x += v0.x; a0.y += v0.y; a0.z += v0.z; a0.w += v0.w;
        }
    } else {
        for (; j + 4 <= s1; j += 4) {
            int i0 = esrc[j], i1 = esrc[j + 1], i2 = esrc[j + 2], i3 = esrc[j + 3];
            uint4 u0 = *(const uint4*)(hP + (size_t)i0 * FH + f);
            uint4 u1 = *(const uint4*)(hP + (size_t)i1 * FH + f);
            uint4 u2 = *(const uint4*)(hP + (size_t)i2 * FH + f);
            uint4 u3 = *(const uint4*)(hP + (size_t)i3 * FH + f);
            a0.x += unpack_f(u0.x); a0.y += unpack_f(u0.y); a0.z += unpack_f(u0.z); a0.w += unpack_f(u0.w);
            a1.x += unpack_f(u1.x); a1.y += unpack_f(u1.y); a1.z += unpack_f(u1.z); a1.w += unpack_f(u1.w);
            a2.x += unpack_f(u2.x); a2.y += unpack_f(u2.y); a2.z += unpack_f(u2.z); a2.w += unpack_f(u2.w);
            a3.x += unpack_f(u3.x); a3.y += unpack_f(u3.y); a3.z += unpack_f(u3.z); a3.w += unpack_f(u3.w);
        }
        for (; j < s1; ++j) {
            uint4 u0 = *(const uint4*)(hP + (size_t)esrc[j] * FH + f);
            a0.x += unpack_f(u0.x); a0.y += unpack_f(u0.y); a0.z += unpack_f(u0.z); a0.w += unpack_f(u0.w);
        }
    }
    float di = dinv[node];
    float vx = (a0.x + a1.x + a2.x + a3.x) * di;
    float vy = (a0.y + a1.y + a2.y + a3.y) * di;
    float vz = (a0.z + a1.z + a2.z + a3.z) * di;
    float vw = (a0.w + a1.w + a2.w + a3.w) * di;
    uint4 o = {pack_bf16pair(vx), pack_bf16pair(vy), pack_bf16pair(vz), pack_bf16pair(vw)};
    *(uint4*)(aggP + (size_t)node * FH + f) = o;
}

// ----------------------------------------------------------- MFMA SAGE GEMM
// 128 threads (2 waves), tile 128 nodes x 128 outs, 12 K-chunks of 64 bf16.
// LDS layout = exact fragment order -> conflict-free b128 both ways.
// Wave w computes n-tiles 4w..4w+3 (16 nodes each) x 8 o-tiles (16 outs).
// mfma_f32_16x16x32_bf16: A[m=lane&15][k=(lane>>4)*8+i]; B[k][n] same pattern;
// D: col(out)=lane&15, row(node)=(lane>>4)*4+reg  [m89-verified].
__global__ __launch_bounds__(128, 2)
void mfma_gemm(const u32* __restrict__ aggP, const u32* __restrict__ hP,
               const u16* __restrict__ Wl, const u16* __restrict__ Wr,
               const float* __restrict__ bias, u32* __restrict__ outP,
               int n_nodes, int do_relu) {
    __shared__ uint4 tiles[2048];  // [0:1024) A frags, [1024:2048) B frags
    int t = threadIdx.x;
    int lane = t & 63;
    int wv = t >> 6;
    int bn0 = blockIdx.x * 128;

    f4frag acc[4][8];
    #pragma unroll
    for (int i = 0; i < 4; ++i)
        #pragma unroll
        for (int o = 0; o < 8; ++o)
            acc[i][o] = (f4frag){0.f, 0.f, 0.f, 0.f};

    int gn = bn0 + t;
    bool valid = (gn < n_nodes);
    int thi = t >> 4, tlo = t & 15;

    for (int c = 0; c < 12; ++c) {
        const u32* P = (c < 6) ? aggP : hP;
        const u16* W = (c < 6) ? Wl : Wr;
        int j = (c < 6) ? c : c - 6;
        int fbase = (j & 1) * 64;
        bool takeHi = (j < 4);

        // ---- stage A (thread t = node t of the tile) ----
        const u32* Ap = P + (size_t)gn * FH + fbase;
        #pragma unroll 2
        for (int u = 0; u < 8; ++u) {
            uint4 p0 = {0u, 0u, 0u, 0u}, p1 = {0u, 0u, 0u, 0u};
            if (valid) {
                p0 = *(const uint4*)(Ap + u * 8);
                p1 = *(const uint4*)(Ap + u * 8 + 4);
            }
            uint4 o;
            if (takeHi) {
                o.x = (p0.x >> 16) | (p0.y & 0xFFFF0000u);
                o.y = (p0.z >> 16) | (p0.w & 0xFFFF0000u);
                o.z = (p1.x >> 16) | (p1.y & 0xFFFF0000u);
                o.w = (p1.z >> 16) | (p1.w & 0xFFFF0000u);
            } else {
                o.x = (p0.x & 0xFFFFu) | (p0.y << 16);
                o.y = (p0.z & 0xFFFFu) | (p0.w << 16);
                o.z = (p1.x & 0xFFFFu) | (p1.y << 16);
                o.w = (p1.z & 0xFFFFu) | (p1.w << 16);
            }
            tiles[(thi * 2 + (u >> 2)) * 64 + tlo + (u & 3) * 16] = o;
        }
        // ---- stage B (thread t = output t) ----
        const u16* Bp = W + (size_t)t * 384 + j * 64;
        #pragma unroll 2
        for (int u = 0; u < 8; ++u) {
            uint4 b = *(const uint4*)(Bp + u * 8);
            tiles[1024 + (thi * 2 + (u >> 2)) * 64 + tlo + (u & 3) * 16] = b;
        }
        __syncthreads();
        // ---- compute ----
        #pragma unroll
        for (int s = 0; s < 2; ++s) {
            bf8frag a[4], b[8];
            #pragma unroll
            for (int i = 0; i < 4; ++i)
                a[i] = *(const bf8frag*)&tiles[((wv * 4 + i) * 2 + s) * 64 + lane];
            #pragma unroll
            for (int o = 0; o < 8; ++o)
                b[o] = *(const bf8frag*)&tiles[1024 + (o * 2 + s) * 64 + lane];
            #pragma unroll
            for (int i = 0; i < 4; ++i)
                #pragma unroll
                for (int o = 0; o < 8; ++o)
                    acc[i][o] = __builtin_amdgcn_mfma_f32_16x16x32_bf16(a[i], b[o], acc[i][o], 0, 0, 0);
        }
        __syncthreads();
    }

    // ---- epilogue: bias (+relu), pack, store ----
    int q = lane >> 4, lo16 = lane & 15;
    #pragma unroll
    for (int i = 0; i < 4; ++i) {
        int nt = wv * 4 + i;
        #pragma unroll
        for (int r = 0; r < 4; ++r) {
            int node = bn0 + nt * 16 + q * 4 + r;
            if (node < n_nodes) {
                #pragma unroll
                for (int ot = 0; ot < 8; ++ot) {
                    int o = ot * 16 + lo16;
                    float v = acc[i][ot][r] + bias[o];
                    if (do_relu) v = fmaxf(v, 0.f);
                    outP[(size_t)node * FH + o] = pack_bf16pair(v);
                }
            }
        }
    }
}

// --------------------------------------------------------------- pooling
__global__ void pool_kernel(const u32* __restrict__ hP, const int* __restrict__ gstart,
                            float* __restrict__ pooled) {
    int g = blockIdx.x;
    int f = threadIdx.x;  // 128
    int s = gstart[g], e = gstart[g + 1];
    float mx = -INFINITY, sum = 0.f;
    for (int n = s; n < e; ++n) {
        float v = unpack_f(hP[(size_t)n * FH + f]);
        mx = fmaxf(mx, v);
        sum += v;
    }
    int c = e - s;
    if (c == 0) mx = 0.f;
    pooled[(size_t)g * (2 * FH) + f] = mx;
    pooled[(size_t)g * (2 * FH) + FH + f] = sum / (float)max(c, 1);
}

// ------------------------------------------------------------ final linear
__global__ void final_gemm(const float* __restrict__ pooled, const float* __restrict__ Wlin,
                           const float* __restrict__ blin, float* __restrict__ out) {
    __shared__ float pr[2 * FH];
    int g = blockIdx.x, o = threadIdx.x;  // 256 threads
    pr[o] = pooled[(size_t)g * (2 * FH) + o];
    __syncthreads();
    const float4* wr = (const float4*)(Wlin + (size_t)o * (2 * FH));
    float acc = 0.f;
    #pragma unroll
    for (int j = 0; j < (2 * FH) / 4; ++j) {
        float4 wv = wr[j];
        acc += wv.x * pr[j * 4 + 0] + wv.y * pr[j * 4 + 1] +
               wv.z * pr[j * 4 + 2] + wv.w * pr[j * 4 + 3];
    }
    out[(size_t)g * OUTD + o] = acc + blin[o];
}

extern "C" void kernel_launch(void* const* d_in, const int* in_sizes, int n_in,
                              void* d_out, int out_size, void* d_ws, size_t ws_size,
                              hipStream_t stream) {
    const float* x     = (const float*)d_in[0];
    const int*   ei    = (const int*)d_in[1];
    const int*   batch = (const int*)d_in[2];
    const float* W1l = (const float*)d_in[3];
    const float* b1  = (const float*)d_in[4];
    const float* W1r = (const float*)d_in[5];
    const float* W2l = (const float*)d_in[6];
    const float* b2  = (const float*)d_in[7];
    const float* W2r = (const float*)d_in[8];
    const float* W3l = (const float*)d_in[9];
    const float* b3  = (const float*)d_in[10];
    const float* W3r = (const float*)d_in[11];
    const float* Wlin = (const float*)d_in[12];
    const float* blin = (const float*)d_in[13];
    float* out = (float*)d_out;

    const int E = in_sizes[1] / 2;
    const int N = in_sizes[2];
    const int G = out_size / OUTD;
    const int* src = ei;
    const int* dst = ei + E;
    const int NB = (N + SCHUNK - 1) / SCHUNK;

    // ---- workspace carve-up ----
    char* w = (char*)d_ws;
    auto alloc = [&](size_t bytes) {
        void* p = (void*)w;
        w += (bytes + 255) & ~(size_t)255;
        return p;
    };
    int*   cnt    = (int*)alloc((size_t)2 * N * sizeof(int));
    int*   cursor = cnt + N;
    int*   rp     = (int*)alloc((size_t)(N + 1) * sizeof(int));
    int*   esrc   = (int*)alloc((size_t)E * sizeof(int));
    int*   gstart = (int*)alloc((size_t)(G + 1) * sizeof(int));
    float* dinv   = (float*)alloc((size_t)N * sizeof(float));
    int*   bsum   = (int*)alloc(64 * sizeof(int));
    int*   boff   = (int*)alloc(64 * sizeof(int));
    u32*   aggP   = (u32*)alloc((size_t)N * FH * sizeof(u32));
    u32*   hPa    = (u32*)alloc((size_t)N * FH * sizeof(u32));
    u32*   hPb    = (u32*)alloc((size_t)N * FH * sizeof(u32));
    u16*   Wp     = (u16*)alloc((size_t)6 * 128 * 384 * sizeof(u16));
    float* pooled = (float*)alloc((size_t)G * 2 * FH * sizeof(float));

    // ---- prep ----
    prep_x<<<(N * 32 + 255) / 256, 256, 0, stream>>>(x, hPa, N * 32);
    prep_w<<<6, 128, 0, stream>>>(W1l, W1r, W2l, W2r, W3l, W3r, Wp);

    // ---- CSR build ----
    hipMemsetAsync(cnt, 0, (size_t)2 * N * sizeof(int), stream);
    hist_kernel<<<(E + 255) / 256, 256, 0, stream>>>(dst, cnt, E);
    scanA_kernel<<<NB, 256, 0, stream>>>(cnt, bsum, N);
    scanB_kernel<<<1, 64, 0, stream>>>(bsum, boff, rp, NB, N);
    scanC_kernel<<<NB, 256, 0, stream>>>(cnt, boff, rp, dinv, N);
    scatter_kernel<<<(E + 255) / 256, 256, 0, stream>>>(src, dst, rp, cursor, esrc, E);
    graph_bounds_kernel<<<(N + 255) / 256, 256, 0, stream>>>(batch, gstart, N, G);

    const int agg_grid  = (N + 7) / 8;
    const int gemm_grid = (N + 127) / 128;
    const size_t WROW = (size_t)128 * 384;

    // ---- layer 1 ----
    agg_kernel<<<agg_grid, 256, 0, stream>>>(x, nullptr, rp, esrc, dinv, aggP, N);
    mfma_gemm<<<gemm_grid, 128, 0, stream>>>(aggP, hPa, Wp + 0 * WROW, Wp + 1 * WROW, b1, hPb, N, 1);
    // ---- layer 2 ----
    agg_kernel<<<agg_grid, 256, 0, stream>>>(nullptr, hPb, rp, esrc, dinv, aggP, N);
    mfma_gemm<<<gemm_grid, 128, 0, stream>>>(aggP, hPb, Wp + 2 * WROW, Wp + 3 * WROW, b2, hPa, N, 1);
    // ---- layer 3 ----
    agg_kernel<<<agg_grid, 256, 0, stream>>>(nullptr, hPa, rp, esrc, dinv, aggP, N);
    mfma_gemm<<<gemm_grid, 128, 0, stream>>>(aggP, hPa, Wp + 4 * WROW, Wp + 5 * WROW, b3, hPb, N, 0);

    // ---- pool + head ----
    pool_kernel<<<G, FH, 0, stream>>>(hPb, gstart, pooled);
    final_gemm<<<G, OUTD, 0, stream>>>(pooled, Wlin, blin, out);
}

// Round 4
// 470.415 us; speedup vs baseline: 1.1298x; 1.1298x over previous
//
#include <hip/hip_runtime.h>
#include <hip/hip_bf16.h>

// GraphSAGE 3-layer + pool + linear.
// R4 GEMM: barrier-free, LDS-free MFMA. One wave per 48-node x 128-out tile.
// A-frags loaded directly from row-major packed activations (u32 = hi|lo bf16):
//   lane l reads node nt*16+(l&15), feats s*32+(l>>4)*8..+7 -> 2 uint4 (128B-line tiled).
// B-frags precomputed in fragment order (prep_w): [ks 12][ot 8][lane 64] uint4.
//   ks 0-3 = Whi, 4-7 = Wlo, 8-11 = Whi (dup); A side uses Ahi,Ahi,Alo.
// Split-bf16: C = Ahi*Whi + Ahi*Wlo + Alo*Whi (drops lo*lo ~2^-18) per source.

#define FH 128
#define OUTD 256
#define SCHUNK 2048

typedef unsigned int u32;
typedef unsigned short u16;
typedef __attribute__((ext_vector_type(8))) short bf8frag;
typedef __attribute__((ext_vector_type(4))) float f4frag;

__device__ inline u32 pack_bf16pair(float v) {
    u32 b = __float_as_uint(v);
    u32 hb = (b + 0x7FFFu + ((b >> 16) & 1u)) & 0xFFFF0000u;
    float rem = v - __uint_as_float(hb);
    u32 rb = __float_as_uint(rem);
    u32 lb = ((rb + 0x7FFFu + ((rb >> 16) & 1u)) >> 16) & 0xFFFFu;
    return hb | lb;
}
__device__ inline float unpack_f(u32 u) {
    return __uint_as_float(u & 0xFFFF0000u) + __uint_as_float(u << 16);
}

// ---------------------------------------------------------------- histogram
__global__ void hist_kernel(const int* __restrict__ dst, int* __restrict__ cnt, int E) {
    int e = blockIdx.x * 256 + threadIdx.x;
    if (e < E) atomicAdd(&cnt[dst[e]], 1);
}

// ---------------------------------------------- scan pass A: per-block sums
__global__ void scanA_kernel(const int* __restrict__ cnt, int* __restrict__ bsum, int n) {
    __shared__ int ws[4];
    int b = blockIdx.x, t = threadIdx.x;
    int base = b * SCHUNK + t * 8;
    int s = 0;
    #pragma unroll
    for (int k = 0; k < 8; ++k) {
        int i = base + k;
        s += (i < n) ? cnt[i] : 0;
    }
    #pragma unroll
    for (int off = 32; off >= 1; off >>= 1) s += __shfl_xor(s, off, 64);
    int w = t >> 6, lane = t & 63;
    if (lane == 0) ws[w] = s;
    __syncthreads();
    if (t == 0) bsum[b] = ws[0] + ws[1] + ws[2] + ws[3];
}

// ------------------------------- scan pass B: scan block sums (1 wave)
__global__ void scanB_kernel(const int* __restrict__ bsum, int* __restrict__ boff,
                             int* __restrict__ rp, int B, int n) {
    int t = threadIdx.x;  // 64 threads
    int v = (t < B) ? bsum[t] : 0;
    int x = v;
    #pragma unroll
    for (int off = 1; off < 64; off <<= 1) {
        int y = __shfl_up(x, off, 64);
        if (t >= off) x += y;
    }
    if (t < B) boff[t] = x - v;
    if (t == 63) rp[n] = x;
}

// --------------------------- scan pass C: full exclusive scan + emit rp/dinv
__global__ void scanC_kernel(const int* __restrict__ cnt, const int* __restrict__ boff,
                             int* __restrict__ rp, float* __restrict__ dinv, int n) {
    __shared__ int ws[4];
    int b = blockIdx.x, t = threadIdx.x;
    int base = b * SCHUNK + t * 8;
    int v[8];
    int ts = 0;
    #pragma unroll
    for (int k = 0; k < 8; ++k) {
        int i = base + k;
        v[k] = (i < n) ? cnt[i] : 0;
        ts += v[k];
    }
    int w = t >> 6, lane = t & 63;
    int x = ts;
    #pragma unroll
    for (int off = 1; off < 64; off <<= 1) {
        int y = __shfl_up(x, off, 64);
        if (lane >= off) x += y;
    }
    if (lane == 63) ws[w] = x;
    __syncthreads();
    int woff = 0;
    #pragma unroll
    for (int q = 0; q < 4; ++q) woff += (q < w) ? ws[q] : 0;
    int run = boff[b] + woff + (x - ts);
    #pragma unroll
    for (int k = 0; k < 8; ++k) {
        int i = base + k;
        if (i < n) {
            rp[i] = run;
            dinv[i] = 1.0f / (float)max(v[k], 1);
        }
        run += v[k];
    }
}

// --------------------------------------------------------- CSR edge scatter
__global__ void scatter_kernel(const int* __restrict__ src, const int* __restrict__ dst,
                               const int* __restrict__ rp, int* __restrict__ cursor,
                               int* __restrict__ esrc, int E) {
    int e = blockIdx.x * 256 + threadIdx.x;
    if (e < E) {
        int d = dst[e];
        int pos = rp[d] + atomicAdd(&cursor[d], 1);
        esrc[pos] = src[e];
    }
}

// ------------------------------------------------------- graph range bounds
__global__ void graph_bounds_kernel(const int* __restrict__ batch, int* __restrict__ gstart,
                                    int n, int g) {
    int i = blockIdx.x * 256 + threadIdx.x;
    if (i >= n) return;
    int b = batch[i];
    int pb = (i == 0) ? -1 : batch[i - 1];
    for (int q = pb + 1; q <= b; ++q) gstart[q] = i;
    if (i == n - 1) {
        for (int q = b + 1; q <= g; ++q) gstart[q] = n;
    }
}

// ---------------------------------------------------------- prep: x -> packed
__global__ void prep_x(const float* __restrict__ x, u32* __restrict__ hP, int n4) {
    int id = blockIdx.x * 256 + threadIdx.x;
    if (id >= n4) return;
    float4 v = *(const float4*)(x + (size_t)id * 4);
    u32 o0 = pack_bf16pair(v.x), o1 = pack_bf16pair(v.y);
    u32 o2 = pack_bf16pair(v.z), o3 = pack_bf16pair(v.w);
    uint4 o = {o0, o1, o2, o3};
    *(uint4*)(hP + (size_t)id * 4) = o;
}

// --------------------- prep: weights -> B fragments in MFMA operand order
// Per array: Bf[(ks*8 + ot)*64 + lane] = uint4 (8 bf16), lane l holds
// W[out=ot*16+(l&15)][k = kbase(ks) + (l>>4)*8 + i], i=0..7.
// ks 0-3: hi, kbase ks*32; ks 4-7: lo, kbase (ks-4)*32; ks 8-11: hi again.
__global__ void prep_w(const float* __restrict__ W0, const float* __restrict__ W1,
                       const float* __restrict__ W2, const float* __restrict__ W3,
                       const float* __restrict__ W4, const float* __restrict__ W5,
                       uint4* __restrict__ Bf) {
    const float* Ws[6] = {W0, W1, W2, W3, W4, W5};
    int ks = blockIdx.x;      // 0..11
    int arr = blockIdx.y;     // 0..5
    int l = threadIdx.x;      // 0..63
    const float* W = Ws[arr];
    bool use_lo = (ks >= 4 && ks < 8);
    int kb = (ks & 3) * 32 + (l >> 4) * 8;
    uint4* out = Bf + (size_t)arr * 6144;
    #pragma unroll
    for (int ot = 0; ot < 8; ++ot) {
        int o = ot * 16 + (l & 15);
        u32 h[8];
        #pragma unroll
        for (int i = 0; i < 8; ++i) {
            float v = W[o * 128 + kb + i];
            u32 b = __float_as_uint(v);
            u32 hb = (b + 0x7FFFu + ((b >> 16) & 1u)) & 0xFFFF0000u;
            if (use_lo) {
                float rem = v - __uint_as_float(hb);
                u32 rb = __float_as_uint(rem);
                h[i] = ((rb + 0x7FFFu + ((rb >> 16) & 1u)) >> 16) & 0xFFFFu;
            } else {
                h[i] = hb >> 16;
            }
        }
        uint4 u;
        u.x = h[0] | (h[1] << 16);
        u.y = h[2] | (h[3] << 16);
        u.z = h[4] | (h[5] << 16);
        u.w = h[6] | (h[7] << 16);
        out[(ks * 8 + ot) * 64 + l] = u;
    }
}

// --------------------------------------------------- mean aggregation (CSR)
// half-wave (32 lanes) per node; lane covers 4 features; x4 unroll for MLP.
__global__ void agg_kernel(const float* __restrict__ xf, const u32* __restrict__ hP,
                           const int* __restrict__ rp, const int* __restrict__ esrc,
                           const float* __restrict__ dinv,
                           u32* __restrict__ aggP, int n_nodes) {
    int node = blockIdx.x * 8 + (threadIdx.x >> 5);
    if (node >= n_nodes) return;
    int lane = threadIdx.x & 31;
    int f = lane * 4;
    int s0 = rp[node], s1 = rp[node + 1];
    float4 a0 = {0.f, 0.f, 0.f, 0.f};
    float4 a1 = a0, a2 = a0, a3 = a0;
    int j = s0;
    if (xf) {
        for (; j + 4 <= s1; j += 4) {
            int i0 = esrc[j], i1 = esrc[j + 1], i2 = esrc[j + 2], i3 = esrc[j + 3];
            float4 v0 = *(const float4*)(xf + (size_t)i0 * FH + f);
            float4 v1 = *(const float4*)(xf + (size_t)i1 * FH + f);
            float4 v2 = *(const float4*)(xf + (size_t)i2 * FH + f);
            float4 v3 = *(const float4*)(xf + (size_t)i3 * FH + f);
            a0.x += v0.x; a0.y += v0.y; a0.z += v0.z; a0.w += v0.w;
            a1.x += v1.x; a1.y += v1.y; a1.z += v1.z; a1.w += v1.w;
            a2.x += v2.x; a2.y += v2.y; a2.z += v2.z; a2.w += v2.w;
            a3.x += v3.x; a3.y += v3.y; a3.z += v3.z; a3.w += v3.w;
        }
        for (; j < s1; ++j) {
            float4 v0 = *(const float4*)(xf + (size_t)esrc[j] * FH + f);
            a0.x += v0.x; a0.y += v0.y; a0.z += v0.z; a0.w += v0.w;
        }
    } else {
        for (; j + 4 <= s1; j += 4) {
            int i0 = esrc[j], i1 = esrc[j + 1], i2 = esrc[j + 2], i3 = esrc[j + 3];
            uint4 u0 = *(const uint4*)(hP + (size_t)i0 * FH + f);
            uint4 u1 = *(const uint4*)(hP + (size_t)i1 * FH + f);
            uint4 u2 = *(const uint4*)(hP + (size_t)i2 * FH + f);
            uint4 u3 = *(const uint4*)(hP + (size_t)i3 * FH + f);
            a0.x += unpack_f(u0.x); a0.y += unpack_f(u0.y); a0.z += unpack_f(u0.z); a0.w += unpack_f(u0.w);
            a1.x += unpack_f(u1.x); a1.y += unpack_f(u1.y); a1.z += unpack_f(u1.z); a1.w += unpack_f(u1.w);
            a2.x += unpack_f(u2.x); a2.y += unpack_f(u2.y); a2.z += unpack_f(u2.z); a2.w += unpack_f(u2.w);
            a3.x += unpack_f(u3.x); a3.y += unpack_f(u3.y); a3.z += unpack_f(u3.z); a3.w += unpack_f(u3.w);
        }
        for (; j < s1; ++j) {
            uint4 u0 = *(const uint4*)(hP + (size_t)esrc[j] * FH + f);
            a0.x += unpack_f(u0.x); a0.y += unpack_f(u0.y); a0.z += unpack_f(u0.z); a0.w += unpack_f(u0.w);
        }
    }
    float di = dinv[node];
    float vx = (a0.x + a1.x + a2.x + a3.x) * di;
    float vy = (a0.y + a1.y + a2.y + a3.y) * di;
    float vz = (a0.z + a1.z + a2.z + a3.z) * di;
    float vw = (a0.w + a1.w + a2.w + a3.w) * di;
    uint4 o = {pack_bf16pair(vx), pack_bf16pair(vy), pack_bf16pair(vz), pack_bf16pair(vw)};
    *(uint4*)(aggP + (size_t)node * FH + f) = o;
}

// ----------------------------------------------------------- MFMA SAGE GEMM
// One wave per block. Tile 48 nodes x 128 outs, acc[3][8]. No LDS, no barriers.
// A-frags direct from global (row-major packed); B-frags from prep_w tables.
// Buffers are padded to a 48-node multiple; pad rows hold finite garbage.
__global__ __launch_bounds__(64, 2)
void mfma_gemm(const u32* __restrict__ A1, const u32* __restrict__ A2,
               const uint4* __restrict__ Bf1, const uint4* __restrict__ Bf2,
               const float* __restrict__ bias, u32* __restrict__ outP,
               int do_relu) {
    int l = threadIdx.x;
    int bn0 = blockIdx.x * 48;
    int m = l & 15, q = l >> 4;  // q in 0..3

    f4frag acc[3][8];
    #pragma unroll
    for (int i = 0; i < 3; ++i)
        #pragma unroll
        for (int o = 0; o < 8; ++o)
            acc[i][o] = (f4frag){0.f, 0.f, 0.f, 0.f};

    #pragma unroll
    for (int p = 0; p < 2; ++p) {
        const u32* P = p ? A2 : A1;
        const uint4* Bf = p ? Bf2 : Bf1;

        // ---- load + extract A fragments (once per source) ----
        bf8frag Ahi[3][4], Alo[3][4];
        #pragma unroll
        for (int nt = 0; nt < 3; ++nt) {
            const u32* ap = P + (size_t)(bn0 + nt * 16 + m) * FH + q * 8;
            #pragma unroll
            for (int s = 0; s < 4; ++s) {
                uint4 p0 = *(const uint4*)(ap + s * 32);
                uint4 p1 = *(const uint4*)(ap + s * 32 + 4);
                uint4 h, lo;
                h.x = (p0.x >> 16) | (p0.y & 0xFFFF0000u);
                h.y = (p0.z >> 16) | (p0.w & 0xFFFF0000u);
                h.z = (p1.x >> 16) | (p1.y & 0xFFFF0000u);
                h.w = (p1.z >> 16) | (p1.w & 0xFFFF0000u);
                lo.x = (p0.x & 0xFFFFu) | (p0.y << 16);
                lo.y = (p0.z & 0xFFFFu) | (p0.w << 16);
                lo.z = (p1.x & 0xFFFFu) | (p1.y << 16);
                lo.w = (p1.z & 0xFFFFu) | (p1.w << 16);
                Ahi[nt][s] = *(bf8frag*)&h;
                Alo[nt][s] = *(bf8frag*)&lo;
            }
        }

        // ---- K loop: 12 ksteps (hi*hi x4, hi*lo x4, lo*hi x4) ----
        #pragma unroll
        for (int ks = 0; ks < 12; ++ks) {
            int s = ks & 3;
            const uint4* bp = Bf + (size_t)(ks * 8) * 64 + l;
            bf8frag b[8];
            #pragma unroll
            for (int ot = 0; ot < 8; ++ot) {
                uint4 bu = bp[ot * 64];
                b[ot] = *(bf8frag*)&bu;
            }
            #pragma unroll
            for (int ot = 0; ot < 8; ++ot) {
                #pragma unroll
                for (int nt = 0; nt < 3; ++nt) {
                    bf8frag a = (ks < 8) ? Ahi[nt][s] : Alo[nt][s];
                    acc[nt][ot] = __builtin_amdgcn_mfma_f32_16x16x32_bf16(a, b[ot], acc[nt][ot], 0, 0, 0);
                }
            }
        }
    }

    // ---- epilogue: bias (+relu), pack, store (D: col=l&15, row=q*4+r) ----
    #pragma unroll
    for (int nt = 0; nt < 3; ++nt) {
        #pragma unroll
        for (int r = 0; r < 4; ++r) {
            int node = bn0 + nt * 16 + q * 4 + r;
            #pragma unroll
            for (int ot = 0; ot < 8; ++ot) {
                int o = ot * 16 + m;
                float v = acc[nt][ot][r] + bias[o];
                if (do_relu) v = fmaxf(v, 0.f);
                outP[(size_t)node * FH + o] = pack_bf16pair(v);
            }
        }
    }
}

// --------------------------------------------------------------- pooling
__global__ void pool_kernel(const u32* __restrict__ hP, const int* __restrict__ gstart,
                            float* __restrict__ pooled) {
    int g = blockIdx.x;
    int f = threadIdx.x;  // 128
    int s = gstart[g], e = gstart[g + 1];
    float mx = -INFINITY, sum = 0.f;
    for (int n = s; n < e; ++n) {
        float v = unpack_f(hP[(size_t)n * FH + f]);
        mx = fmaxf(mx, v);
        sum += v;
    }
    int c = e - s;
    if (c == 0) mx = 0.f;
    pooled[(size_t)g * (2 * FH) + f] = mx;
    pooled[(size_t)g * (2 * FH) + FH + f] = sum / (float)max(c, 1);
}

// ------------------------------------------------------------ final linear
__global__ void final_gemm(const float* __restrict__ pooled, const float* __restrict__ Wlin,
                           const float* __restrict__ blin, float* __restrict__ out) {
    __shared__ float pr[2 * FH];
    int g = blockIdx.x, o = threadIdx.x;  // 256 threads
    pr[o] = pooled[(size_t)g * (2 * FH) + o];
    __syncthreads();
    const float4* wr = (const float4*)(Wlin + (size_t)o * (2 * FH));
    float acc = 0.f;
    #pragma unroll
    for (int j = 0; j < (2 * FH) / 4; ++j) {
        float4 wv = wr[j];
        acc += wv.x * pr[j * 4 + 0] + wv.y * pr[j * 4 + 1] +
               wv.z * pr[j * 4 + 2] + wv.w * pr[j * 4 + 3];
    }
    out[(size_t)g * OUTD + o] = acc + blin[o];
}

extern "C" void kernel_launch(void* const* d_in, const int* in_sizes, int n_in,
                              void* d_out, int out_size, void* d_ws, size_t ws_size,
                              hipStream_t stream) {
    const float* x     = (const float*)d_in[0];
    const int*   ei    = (const int*)d_in[1];
    const int*   batch = (const int*)d_in[2];
    const float* W1l = (const float*)d_in[3];
    const float* b1  = (const float*)d_in[4];
    const float* W1r = (const float*)d_in[5];
    const float* W2l = (const float*)d_in[6];
    const float* b2  = (const float*)d_in[7];
    const float* W2r = (const float*)d_in[8];
    const float* W3l = (const float*)d_in[9];
    const float* b3  = (const float*)d_in[10];
    const float* W3r = (const float*)d_in[11];
    const float* Wlin = (const float*)d_in[12];
    const float* blin = (const float*)d_in[13];
    float* out = (float*)d_out;

    const int E = in_sizes[1] / 2;
    const int N = in_sizes[2];
    const int G = out_size / OUTD;
    const int* src = ei;
    const int* dst = ei + E;
    const int NB = (N + SCHUNK - 1) / SCHUNK;
    const int GB = (N + 47) / 48;     // gemm blocks (48-node tiles)
    const int NP = GB * 48;           // padded node count

    // ---- workspace carve-up ----
    char* w = (char*)d_ws;
    auto alloc = [&](size_t bytes) {
        void* p = (void*)w;
        w += (bytes + 255) & ~(size_t)255;
        return p;
    };
    int*   cnt    = (int*)alloc((size_t)2 * N * sizeof(int));
    int*   cursor = cnt + N;
    int*   rp     = (int*)alloc((size_t)(N + 1) * sizeof(int));
    int*   esrc   = (int*)alloc((size_t)E * sizeof(int));
    int*   gstart = (int*)alloc((size_t)(G + 1) * sizeof(int));
    float* dinv   = (float*)alloc((size_t)N * sizeof(float));
    int*   bsum   = (int*)alloc(64 * sizeof(int));
    int*   boff   = (int*)alloc(64 * sizeof(int));
    u32*   aggP   = (u32*)alloc((size_t)NP * FH * sizeof(u32));
    u32*   hPa    = (u32*)alloc((size_t)NP * FH * sizeof(u32));
    u32*   hPb    = (u32*)alloc((size_t)NP * FH * sizeof(u32));
    uint4* BF     = (uint4*)alloc((size_t)6 * 6144 * sizeof(uint4));  // 6 x 96KB
    float* pooled = (float*)alloc((size_t)G * 2 * FH * sizeof(float));

    // ---- prep ----
    prep_x<<<(N * 32 + 255) / 256, 256, 0, stream>>>(x, hPa, N * 32);
    prep_w<<<dim3(12, 6), 64, 0, stream>>>(W1l, W1r, W2l, W2r, W3l, W3r, BF);

    // ---- CSR build ----
    hipMemsetAsync(cnt, 0, (size_t)2 * N * sizeof(int), stream);
    hist_kernel<<<(E + 255) / 256, 256, 0, stream>>>(dst, cnt, E);
    scanA_kernel<<<NB, 256, 0, stream>>>(cnt, bsum, N);
    scanB_kernel<<<1, 64, 0, stream>>>(bsum, boff, rp, NB, N);
    scanC_kernel<<<NB, 256, 0, stream>>>(cnt, boff, rp, dinv, N);
    scatter_kernel<<<(E + 255) / 256, 256, 0, stream>>>(src, dst, rp, cursor, esrc, E);
    graph_bounds_kernel<<<(N + 255) / 256, 256, 0, stream>>>(batch, gstart, N, G);

    const int agg_grid = (N + 7) / 8;

    // ---- layer 1 ----
    agg_kernel<<<agg_grid, 256, 0, stream>>>(x, nullptr, rp, esrc, dinv, aggP, N);
    mfma_gemm<<<GB, 64, 0, stream>>>(aggP, hPa, BF + 0 * 6144, BF + 1 * 6144, b1, hPb, 1);
    // ---- layer 2 ----
    agg_kernel<<<agg_grid, 256, 0, stream>>>(nullptr, hPb, rp, esrc, dinv, aggP, N);
    mfma_gemm<<<GB, 64, 0, stream>>>(aggP, hPb, BF + 2 * 6144, BF + 3 * 6144, b2, hPa, 1);
    // ---- layer 3 ----
    agg_kernel<<<agg_grid, 256, 0, stream>>>(nullptr, hPa, rp, esrc, dinv, aggP, N);
    mfma_gemm<<<GB, 64, 0, stream>>>(aggP, hPa, BF + 4 * 6144, BF + 5 * 6144, b3, hPb, 0);

    // ---- pool + head ----
    pool_kernel<<<G, FH, 0, stream>>>(hPb, gstart, pooled);
    final_gemm<<<G, OUTD, 0, stream>>>(pooled, Wlin, blin, out);
}

// Round 5
// 403.423 us; speedup vs baseline: 1.3174x; 1.1661x over previous
//
#include <hip/hip_runtime.h>
#include <hip/hip_bf16.h>
#include <hip/hip_fp16.h>

// GraphSAGE 3-layer + pool + linear.
// R5: agg gathers an fp16 mirror of activations (256 B/edge, half of R4) while
// GEMM keeps exact split-bf16 packed arrays (u32 = hi|lo bf16).
// GEMM: barrier-free, LDS-free, 1 wave / 48-node x 128-out tile; per-s k-slices
// reuse Bhi for both Ahi*Bhi and Alo*Bhi (no dup table read, ~200 live VGPRs).

#define FH 128
#define OUTD 256
#define SCHUNK 2048

typedef unsigned int u32;
typedef unsigned short u16;
typedef __attribute__((ext_vector_type(8))) short bf8frag;
typedef __attribute__((ext_vector_type(4))) float f4frag;

__device__ inline u32 pack_bf16pair(float v) {
    u32 b = __float_as_uint(v);
    u32 hb = (b + 0x7FFFu + ((b >> 16) & 1u)) & 0xFFFF0000u;
    float rem = v - __uint_as_float(hb);
    u32 rb = __float_as_uint(rem);
    u32 lb = ((rb + 0x7FFFu + ((rb >> 16) & 1u)) >> 16) & 0xFFFFu;
    return hb | lb;
}
__device__ inline float unpack_f(u32 u) {
    return __uint_as_float(u & 0xFFFF0000u) + __uint_as_float(u << 16);
}

// ---------------------------------------------------------------- histogram
__global__ void hist_kernel(const int* __restrict__ dst, int* __restrict__ cnt, int E) {
    int e = blockIdx.x * 256 + threadIdx.x;
    if (e < E) atomicAdd(&cnt[dst[e]], 1);
}

// ---------------------------------------------- scan pass A: per-block sums
__global__ void scanA_kernel(const int* __restrict__ cnt, int* __restrict__ bsum, int n) {
    __shared__ int ws[4];
    int b = blockIdx.x, t = threadIdx.x;
    int base = b * SCHUNK + t * 8;
    int s = 0;
    #pragma unroll
    for (int k = 0; k < 8; ++k) {
        int i = base + k;
        s += (i < n) ? cnt[i] : 0;
    }
    #pragma unroll
    for (int off = 32; off >= 1; off >>= 1) s += __shfl_xor(s, off, 64);
    int w = t >> 6, lane = t & 63;
    if (lane == 0) ws[w] = s;
    __syncthreads();
    if (t == 0) bsum[b] = ws[0] + ws[1] + ws[2] + ws[3];
}

// ------------------------------- scan pass B: scan block sums (1 wave)
__global__ void scanB_kernel(const int* __restrict__ bsum, int* __restrict__ boff,
                             int* __restrict__ rp, int B, int n) {
    int t = threadIdx.x;  // 64 threads
    int v = (t < B) ? bsum[t] : 0;
    int x = v;
    #pragma unroll
    for (int off = 1; off < 64; off <<= 1) {
        int y = __shfl_up(x, off, 64);
        if (t >= off) x += y;
    }
    if (t < B) boff[t] = x - v;
    if (t == 63) rp[n] = x;
}

// --------------------------- scan pass C: full exclusive scan + emit rp/dinv
__global__ void scanC_kernel(const int* __restrict__ cnt, const int* __restrict__ boff,
                             int* __restrict__ rp, float* __restrict__ dinv, int n) {
    __shared__ int ws[4];
    int b = blockIdx.x, t = threadIdx.x;
    int base = b * SCHUNK + t * 8;
    int v[8];
    int ts = 0;
    #pragma unroll
    for (int k = 0; k < 8; ++k) {
        int i = base + k;
        v[k] = (i < n) ? cnt[i] : 0;
        ts += v[k];
    }
    int w = t >> 6, lane = t & 63;
    int x = ts;
    #pragma unroll
    for (int off = 1; off < 64; off <<= 1) {
        int y = __shfl_up(x, off, 64);
        if (lane >= off) x += y;
    }
    if (lane == 63) ws[w] = x;
    __syncthreads();
    int woff = 0;
    #pragma unroll
    for (int q = 0; q < 4; ++q) woff += (q < w) ? ws[q] : 0;
    int run = boff[b] + woff + (x - ts);
    #pragma unroll
    for (int k = 0; k < 8; ++k) {
        int i = base + k;
        if (i < n) {
            rp[i] = run;
            dinv[i] = 1.0f / (float)max(v[k], 1);
        }
        run += v[k];
    }
}

// --------------------------------------------------------- CSR edge scatter
__global__ void scatter_kernel(const int* __restrict__ src, const int* __restrict__ dst,
                               const int* __restrict__ rp, int* __restrict__ cursor,
                               int* __restrict__ esrc, int E) {
    int e = blockIdx.x * 256 + threadIdx.x;
    if (e < E) {
        int d = dst[e];
        int pos = rp[d] + atomicAdd(&cursor[d], 1);
        esrc[pos] = src[e];
    }
}

// ------------------------------------------------------- graph range bounds
__global__ void graph_bounds_kernel(const int* __restrict__ batch, int* __restrict__ gstart,
                                    int n, int g) {
    int i = blockIdx.x * 256 + threadIdx.x;
    if (i >= n) return;
    int b = batch[i];
    int pb = (i == 0) ? -1 : batch[i - 1];
    for (int q = pb + 1; q <= b; ++q) gstart[q] = i;
    if (i == n - 1) {
        for (int q = b + 1; q <= g; ++q) gstart[q] = n;
    }
}

// --------------------------------- prep: x -> packed bf16-pair + fp16 mirror
__global__ void prep_x(const float* __restrict__ x, u32* __restrict__ hP,
                       u16* __restrict__ x16, int n4) {
    int id = blockIdx.x * 256 + threadIdx.x;
    if (id >= n4) return;
    float4 v = *(const float4*)(x + (size_t)id * 4);
    uint4 o = {pack_bf16pair(v.x), pack_bf16pair(v.y), pack_bf16pair(v.z), pack_bf16pair(v.w)};
    *(uint4*)(hP + (size_t)id * 4) = o;
    __half h0 = __float2half(v.x), h1 = __float2half(v.y);
    __half h2 = __float2half(v.z), h3 = __float2half(v.w);
    ushort4 s;
    s.x = *(u16*)&h0; s.y = *(u16*)&h1; s.z = *(u16*)&h2; s.w = *(u16*)&h3;
    *(ushort4*)(x16 + (size_t)id * 4) = s;
}

// --------------------- prep: weights -> B fragments in MFMA operand order
// Per array: Bf[(ks*8 + ot)*64 + lane], lane l holds
// W[out=ot*16+(l&15)][k = (ks&3)*32 + (l>>4)*8 + i], i=0..7.
// ks 0-3: hi part, ks 4-7: lo part.
__global__ void prep_w(const float* __restrict__ W0, const float* __restrict__ W1,
                       const float* __restrict__ W2, const float* __restrict__ W3,
                       const float* __restrict__ W4, const float* __restrict__ W5,
                       uint4* __restrict__ Bf) {
    const float* Ws[6] = {W0, W1, W2, W3, W4, W5};
    int ks = blockIdx.x;      // 0..7
    int arr = blockIdx.y;     // 0..5
    int l = threadIdx.x;      // 0..63
    const float* W = Ws[arr];
    bool use_lo = (ks >= 4);
    int kb = (ks & 3) * 32 + (l >> 4) * 8;
    uint4* out = Bf + (size_t)arr * 4096;
    #pragma unroll
    for (int ot = 0; ot < 8; ++ot) {
        int o = ot * 16 + (l & 15);
        u32 h[8];
        #pragma unroll
        for (int i = 0; i < 8; ++i) {
            float v = W[o * 128 + kb + i];
            u32 b = __float_as_uint(v);
            u32 hb = (b + 0x7FFFu + ((b >> 16) & 1u)) & 0xFFFF0000u;
            if (use_lo) {
                float rem = v - __uint_as_float(hb);
                u32 rb = __float_as_uint(rem);
                h[i] = ((rb + 0x7FFFu + ((rb >> 16) & 1u)) >> 16) & 0xFFFFu;
            } else {
                h[i] = hb >> 16;
            }
        }
        uint4 u;
        u.x = h[0] | (h[1] << 16);
        u.y = h[2] | (h[3] << 16);
        u.z = h[4] | (h[5] << 16);
        u.w = h[6] | (h[7] << 16);
        out[(ks * 8 + ot) * 64 + l] = u;
    }
}

// --------------------------------------------------- mean aggregation (CSR)
// 16 lanes per node; lane covers 8 fp16 features (uint4 = 16B); x4 edge unroll
// -> 4 independent 256B gathers in flight per node group. 256 B/edge (was 512).
__device__ inline void add8(float* a, uint4 u) {
    float2 f0 = __half22float2(*(__half2*)&u.x);
    float2 f1 = __half22float2(*(__half2*)&u.y);
    float2 f2 = __half22float2(*(__half2*)&u.z);
    float2 f3 = __half22float2(*(__half2*)&u.w);
    a[0] += f0.x; a[1] += f0.y; a[2] += f1.x; a[3] += f1.y;
    a[4] += f2.x; a[5] += f2.y; a[6] += f3.x; a[7] += f3.y;
}

__global__ void agg_kernel(const u16* __restrict__ h16,
                           const int* __restrict__ rp, const int* __restrict__ esrc,
                           const float* __restrict__ dinv,
                           u32* __restrict__ aggP, int n_nodes) {
    int node = blockIdx.x * 16 + (threadIdx.x >> 4);
    if (node >= n_nodes) return;
    int lane = threadIdx.x & 15;
    int f = lane * 8;
    int s0 = rp[node], s1 = rp[node + 1];
    float a0[8] = {0, 0, 0, 0, 0, 0, 0, 0};
    float a1[8] = {0, 0, 0, 0, 0, 0, 0, 0};
    float a2[8] = {0, 0, 0, 0, 0, 0, 0, 0};
    float a3[8] = {0, 0, 0, 0, 0, 0, 0, 0};
    int j = s0;
    for (; j + 4 <= s1; j += 4) {
        int i0 = esrc[j], i1 = esrc[j + 1], i2 = esrc[j + 2], i3 = esrc[j + 3];
        uint4 u0 = *(const uint4*)(h16 + (size_t)i0 * FH + f);
        uint4 u1 = *(const uint4*)(h16 + (size_t)i1 * FH + f);
        uint4 u2 = *(const uint4*)(h16 + (size_t)i2 * FH + f);
        uint4 u3 = *(const uint4*)(h16 + (size_t)i3 * FH + f);
        add8(a0, u0); add8(a1, u1); add8(a2, u2); add8(a3, u3);
    }
    for (; j < s1; ++j) {
        uint4 u0 = *(const uint4*)(h16 + (size_t)esrc[j] * FH + f);
        add8(a0, u0);
    }
    float di = dinv[node];
    u32 o[8];
    #pragma unroll
    for (int i = 0; i < 8; ++i)
        o[i] = pack_bf16pair((a0[i] + a1[i] + a2[i] + a3[i]) * di);
    uint4 w0 = {o[0], o[1], o[2], o[3]};
    uint4 w1 = {o[4], o[5], o[6], o[7]};
    *(uint4*)(aggP + (size_t)node * FH + f) = w0;
    *(uint4*)(aggP + (size_t)node * FH + f + 4) = w1;
}

// ----------------------------------------------------------- MFMA SAGE GEMM
// One wave per block. Tile 48 nodes x 128 outs, acc[3][8]. No LDS, no barriers.
// Per k-slice s: load Ahi/Alo (3 frags each) + Bhi/Blo (8 frags each);
// products Ahi*Bhi + Ahi*Blo + Alo*Bhi (split-bf16, drops lo*lo ~2^-18).
__global__ __launch_bounds__(64, 2)
void mfma_gemm(const u32* __restrict__ A1, const u32* __restrict__ A2,
               const uint4* __restrict__ Bf1, const uint4* __restrict__ Bf2,
               const float* __restrict__ bias, u32* __restrict__ outP,
               u16* __restrict__ out16, int do_relu) {
    int l = threadIdx.x;
    int bn0 = blockIdx.x * 48;
    int m = l & 15, q = l >> 4;  // q in 0..3

    f4frag acc[3][8];
    #pragma unroll
    for (int i = 0; i < 3; ++i)
        #pragma unroll
        for (int o = 0; o < 8; ++o)
            acc[i][o] = (f4frag){0.f, 0.f, 0.f, 0.f};

    #pragma unroll
    for (int p = 0; p < 2; ++p) {
        const u32* P = p ? A2 : A1;
        const uint4* Bf = p ? Bf2 : Bf1;

        #pragma unroll
        for (int s = 0; s < 4; ++s) {
            // ---- A frags for this k-slice ----
            bf8frag Ahi[3], Alo[3];
            #pragma unroll
            for (int nt = 0; nt < 3; ++nt) {
                const u32* ap = P + (size_t)(bn0 + nt * 16 + m) * FH + q * 8 + s * 32;
                uint4 p0 = *(const uint4*)(ap);
                uint4 p1 = *(const uint4*)(ap + 4);
                uint4 h, lo;
                h.x = (p0.x >> 16) | (p0.y & 0xFFFF0000u);
                h.y = (p0.z >> 16) | (p0.w & 0xFFFF0000u);
                h.z = (p1.x >> 16) | (p1.y & 0xFFFF0000u);
                h.w = (p1.z >> 16) | (p1.w & 0xFFFF0000u);
                lo.x = (p0.x & 0xFFFFu) | (p0.y << 16);
                lo.y = (p0.z & 0xFFFFu) | (p0.w << 16);
                lo.z = (p1.x & 0xFFFFu) | (p1.y << 16);
                lo.w = (p1.z & 0xFFFFu) | (p1.w << 16);
                Ahi[nt] = *(bf8frag*)&h;
                Alo[nt] = *(bf8frag*)&lo;
            }
            // ---- B frags ----
            bf8frag Bhi[8], Blo[8];
            #pragma unroll
            for (int ot = 0; ot < 8; ++ot) {
                uint4 bh = Bf[(size_t)((s)     * 8 + ot) * 64 + l];
                uint4 bl = Bf[(size_t)((s + 4) * 8 + ot) * 64 + l];
                Bhi[ot] = *(bf8frag*)&bh;
                Blo[ot] = *(bf8frag*)&bl;
            }
            // ---- 72 MFMAs, 24 independent acc chains per pass ----
            #pragma unroll
            for (int ot = 0; ot < 8; ++ot)
                #pragma unroll
                for (int nt = 0; nt < 3; ++nt)
                    acc[nt][ot] = __builtin_amdgcn_mfma_f32_16x16x32_bf16(Ahi[nt], Bhi[ot], acc[nt][ot], 0, 0, 0);
            #pragma unroll
            for (int ot = 0; ot < 8; ++ot)
                #pragma unroll
                for (int nt = 0; nt < 3; ++nt)
                    acc[nt][ot] = __builtin_amdgcn_mfma_f32_16x16x32_bf16(Ahi[nt], Blo[ot], acc[nt][ot], 0, 0, 0);
            #pragma unroll
            for (int ot = 0; ot < 8; ++ot)
                #pragma unroll
                for (int nt = 0; nt < 3; ++nt)
                    acc[nt][ot] = __builtin_amdgcn_mfma_f32_16x16x32_bf16(Alo[nt], Bhi[ot], acc[nt][ot], 0, 0, 0);
        }
    }

    // ---- epilogue: bias (+relu), pack, store (D: col=l&15, row=q*4+r) ----
    float vout[3][4][8];
    #pragma unroll
    for (int nt = 0; nt < 3; ++nt)
        #pragma unroll
        for (int r = 0; r < 4; ++r)
            #pragma unroll
            for (int ot = 0; ot < 8; ++ot) {
                float v = acc[nt][ot][r] + bias[ot * 16 + m];
                if (do_relu) v = fmaxf(v, 0.f);
                vout[nt][r][ot] = v;
            }
    #pragma unroll
    for (int nt = 0; nt < 3; ++nt)
        #pragma unroll
        for (int r = 0; r < 4; ++r) {
            int node = bn0 + nt * 16 + q * 4 + r;
            #pragma unroll
            for (int ot = 0; ot < 8; ++ot)
                outP[(size_t)node * FH + ot * 16 + m] = pack_bf16pair(vout[nt][r][ot]);
        }
    if (out16) {
        #pragma unroll
        for (int nt = 0; nt < 3; ++nt)
            #pragma unroll
            for (int r = 0; r < 4; ++r) {
                int node = bn0 + nt * 16 + q * 4 + r;
                #pragma unroll
                for (int ot = 0; ot < 8; ++ot) {
                    __half h = __float2half(vout[nt][r][ot]);
                    out16[(size_t)node * FH + ot * 16 + m] = *(u16*)&h;
                }
            }
    }
}

// --------------------------------------------------------------- pooling
__global__ void pool_kernel(const u32* __restrict__ hP, const int* __restrict__ gstart,
                            float* __restrict__ pooled) {
    int g = blockIdx.x;
    int f = threadIdx.x;  // 128
    int s = gstart[g], e = gstart[g + 1];
    float mx = -INFINITY, sum = 0.f;
    for (int n = s; n < e; ++n) {
        float v = unpack_f(hP[(size_t)n * FH + f]);
        mx = fmaxf(mx, v);
        sum += v;
    }
    int c = e - s;
    if (c == 0) mx = 0.f;
    pooled[(size_t)g * (2 * FH) + f] = mx;
    pooled[(size_t)g * (2 * FH) + FH + f] = sum / (float)max(c, 1);
}

// ------------------------------------------------------------ final linear
__global__ void final_gemm(const float* __restrict__ pooled, const float* __restrict__ Wlin,
                           const float* __restrict__ blin, float* __restrict__ out) {
    __shared__ float pr[2 * FH];
    int g = blockIdx.x, o = threadIdx.x;  // 256 threads
    pr[o] = pooled[(size_t)g * (2 * FH) + o];
    __syncthreads();
    const float4* wr = (const float4*)(Wlin + (size_t)o * (2 * FH));
    float acc = 0.f;
    #pragma unroll
    for (int j = 0; j < (2 * FH) / 4; ++j) {
        float4 wv = wr[j];
        acc += wv.x * pr[j * 4 + 0] + wv.y * pr[j * 4 + 1] +
               wv.z * pr[j * 4 + 2] + wv.w * pr[j * 4 + 3];
    }
    out[(size_t)g * OUTD + o] = acc + blin[o];
}

extern "C" void kernel_launch(void* const* d_in, const int* in_sizes, int n_in,
                              void* d_out, int out_size, void* d_ws, size_t ws_size,
                              hipStream_t stream) {
    const float* x     = (const float*)d_in[0];
    const int*   ei    = (const int*)d_in[1];
    const int*   batch = (const int*)d_in[2];
    const float* W1l = (const float*)d_in[3];
    const float* b1  = (const float*)d_in[4];
    const float* W1r = (const float*)d_in[5];
    const float* W2l = (const float*)d_in[6];
    const float* b2  = (const float*)d_in[7];
    const float* W2r = (const float*)d_in[8];
    const float* W3l = (const float*)d_in[9];
    const float* b3  = (const float*)d_in[10];
    const float* W3r = (const float*)d_in[11];
    const float* Wlin = (const float*)d_in[12];
    const float* blin = (const float*)d_in[13];
    float* out = (float*)d_out;

    const int E = in_sizes[1] / 2;
    const int N = in_sizes[2];
    const int G = out_size / OUTD;
    const int* src = ei;
    const int* dst = ei + E;
    const int NB = (N + SCHUNK - 1) / SCHUNK;
    const int GB = (N + 47) / 48;     // gemm blocks (48-node tiles)
    const int NP = GB * 48;           // padded node count

    // ---- workspace carve-up ----
    char* w = (char*)d_ws;
    auto alloc = [&](size_t bytes) {
        void* p = (void*)w;
        w += (bytes + 255) & ~(size_t)255;
        return p;
    };
    int*   cnt    = (int*)alloc((size_t)2 * N * sizeof(int));
    int*   cursor = cnt + N;
    int*   rp     = (int*)alloc((size_t)(N + 1) * sizeof(int));
    int*   esrc   = (int*)alloc((size_t)E * sizeof(int));
    int*   gstart = (int*)alloc((size_t)(G + 1) * sizeof(int));
    float* dinv   = (float*)alloc((size_t)N * sizeof(float));
    int*   bsum   = (int*)alloc(64 * sizeof(int));
    int*   boff   = (int*)alloc(64 * sizeof(int));
    u32*   aggP   = (u32*)alloc((size_t)NP * FH * sizeof(u32));
    u32*   hPa    = (u32*)alloc((size_t)NP * FH * sizeof(u32));
    u32*   hPb    = (u32*)alloc((size_t)NP * FH * sizeof(u32));
    u16*   F16A   = (u16*)alloc((size_t)NP * FH * sizeof(u16));
    u16*   F16B   = (u16*)alloc((size_t)NP * FH * sizeof(u16));
    uint4* BF     = (uint4*)alloc((size_t)6 * 4096 * sizeof(uint4));  // 6 x 64KB
    float* pooled = (float*)alloc((size_t)G * 2 * FH * sizeof(float));

    // ---- prep ----
    prep_x<<<(N * 32 + 255) / 256, 256, 0, stream>>>(x, hPa, F16A, N * 32);
    prep_w<<<dim3(8, 6), 64, 0, stream>>>(W1l, W1r, W2l, W2r, W3l, W3r, BF);

    // ---- CSR build ----
    hipMemsetAsync(cnt, 0, (size_t)2 * N * sizeof(int), stream);
    hist_kernel<<<(E + 255) / 256, 256, 0, stream>>>(dst, cnt, E);
    scanA_kernel<<<NB, 256, 0, stream>>>(cnt, bsum, N);
    scanB_kernel<<<1, 64, 0, stream>>>(bsum, boff, rp, NB, N);
    scanC_kernel<<<NB, 256, 0, stream>>>(cnt, boff, rp, dinv, N);
    scatter_kernel<<<(E + 255) / 256, 256, 0, stream>>>(src, dst, rp, cursor, esrc, E);
    graph_bounds_kernel<<<(N + 255) / 256, 256, 0, stream>>>(batch, gstart, N, G);

    const int agg_grid = (N + 15) / 16;

    // ---- layer 1 ----
    agg_kernel<<<agg_grid, 256, 0, stream>>>(F16A, rp, esrc, dinv, aggP, N);
    mfma_gemm<<<GB, 64, 0, stream>>>(aggP, hPa, BF + 0 * 4096, BF + 1 * 4096, b1, hPb, F16B, 1);
    // ---- layer 2 ----
    agg_kernel<<<agg_grid, 256, 0, stream>>>(F16B, rp, esrc, dinv, aggP, N);
    mfma_gemm<<<GB, 64, 0, stream>>>(aggP, hPb, BF + 2 * 4096, BF + 3 * 4096, b2, hPa, F16A, 1);
    // ---- layer 3 ----
    agg_kernel<<<agg_grid, 256, 0, stream>>>(F16A, rp, esrc, dinv, aggP, N);
    mfma_gemm<<<GB, 64, 0, stream>>>(aggP, hPa, BF + 4 * 4096, BF + 5 * 4096, b3, hPb, (u16*)nullptr, 0);

    // ---- pool + head ----
    pool_kernel<<<G, FH, 0, stream>>>(hPb, gstart, pooled);
    final_gemm<<<G, OUTD, 0, stream>>>(pooled, Wlin, blin, out);
}